// Round 8
// baseline (408.701 us; speedup 1.0000x reference)
//
#include <hip/hip_runtime.h>
#include <math.h>

#define B_   24
#define NA_  50
#define T_   10
#define NV_  196
#define D_   512
#define M_   1200          // B*NA audio rows
#define MPAD 1280          // padded to 10 tiles of 128
#define NVP  224           // 196 padded to 14*16
#define YT_  240           // B*T
#define VROWS (YT_ * NVP)  // 53760 padded visual rows
#define ABLK 320           // MPAD/4 blocks handle audio in fused normconv

typedef __bf16 bf16x8 __attribute__((ext_vector_type(8)));
typedef float  f32x4  __attribute__((ext_vector_type(4)));
typedef unsigned short ushort8 __attribute__((ext_vector_type(8)));

__device__ __forceinline__ unsigned short f2bf(float f) {
    unsigned u = __float_as_uint(f);
    u += 0x7FFF + ((u >> 16) & 1);       // RNE
    return (unsigned short)(u >> 16);
}

// ---- fused L2-normalize + bf16 convert for BOTH inputs, + accs/counter zeroing ----
// blocks [0, ABLK): audio rows (scaled by 1/temperature); [ABLK, ...): visual rows.
__global__ void normconv_kernel(const float* __restrict__ a,
                                const float* __restrict__ vf,
                                const float* __restrict__ tempPtr,
                                unsigned short* __restrict__ Abf,
                                unsigned short* __restrict__ Vbf,
                                float* __restrict__ accs) {
    if (blockIdx.x == 0 && threadIdx.x < 4) accs[threadIdx.x] = 0.0f; // [nonneg,frac,sel,counter]
    int w = threadIdx.x >> 6, lane = threadIdx.x & 63;
    int bid = blockIdx.x;
    const float* src = nullptr;
    ushort8* dst;
    float tscale = 1.0f;
    if (bid < ABLK) {
        int row = bid * 4 + w;                 // < MPAD
        dst = (ushort8*)(Abf + (size_t)row * D_ + lane * 8);
        if (row < M_) { src = a + (size_t)row * D_ + lane * 8; tscale = tempPtr[0]; }
    } else {
        int row = (bid - ABLK) * 4 + w;        // < VROWS
        dst = (ushort8*)(Vbf + (size_t)row * D_ + lane * 8);
        int yt = row / NVP, vv = row - yt * NVP;
        if (vv < NV_) src = vf + ((size_t)yt * NV_ + vv) * D_ + lane * 8;
    }
    if (src) {
        float4 u = *(const float4*)src;
        float4 v = *(const float4*)(src + 4);
        float s = u.x*u.x + u.y*u.y + u.z*u.z + u.w*u.w
                + v.x*v.x + v.y*v.y + v.z*v.z + v.w*v.w;
        #pragma unroll
        for (int off = 32; off; off >>= 1) s += __shfl_xor(s, off, 64);
        float sc = 1.0f / (fmaxf(sqrtf(s), 1e-12f) * tscale);
        ushort8 o;
        o[0]=f2bf(u.x*sc); o[1]=f2bf(u.y*sc); o[2]=f2bf(u.z*sc); o[3]=f2bf(u.w*sc);
        o[4]=f2bf(v.x*sc); o[5]=f2bf(v.y*sc); o[6]=f2bf(v.z*sc); o[7]=f2bf(v.w*sc);
        *dst = o;
    } else {
        ushort8 z = (ushort8)0;
        *dst = z;
    }
}

// ---- MFMA GEMM + fused max/clip reductions, DIRECT-REGISTER + XCD swizzle ----
// R2's barrier-free, LDS-free structure (fully-unrolled K loop, fragment
// loads straight from global with immediate chunk offsets, compiler-counted
// vmcnt pipelining) combined with R3's XCD-aware bijective block swizzle
// (keeps each XCD's V working set L2-resident; FETCH 229->32 MB verified).
// R2 alone = 239us in the HBM-thrash regime; the swizzle removes the thrash:
// loads become ~250cyc L2 hits, hidden per-wave under the 543cyc MFMA phase
// with no barrier lockstep (which capped every LDS variant at 109-122us).
// Each fragment load instruction reads 16 dense 64B lines (fully coalesced);
// wave pairs share A/B fragments through L1 (22KB/chunk < 32KB).
__global__ __launch_bounds__(256, 2) void simred_kernel(
    const unsigned short* __restrict__ Abf, const unsigned short* __restrict__ Vbf,
    float* __restrict__ maxvis, float* __restrict__ accNonneg)
{
    __shared__ float maxred[2][128];
    __shared__ float redbuf[4];

    const int tid  = threadIdx.x;
    const int lane = tid & 63;
    const int w    = tid >> 6;
    const int q    = lane >> 4;    // frag quad: k-segment q*8..q*8+7
    const int m16  = lane & 15;    // frag row/col within 16
    const int wr   = w & 1;        // wave row half (64 rows)
    const int wc   = w >> 1;       // wave col half (112 cols)

    // XCD-aware bijective remap: 2400 blocks, 8 XCDs, 300 blocks/XCD.
    // lin%8 = XCD (round-robin dispatch); XCD x owns swz [300x, 300x+300)
    // -> yt in [30x, 30x+30), bx fastest (R3-verified L2-resident partition).
    const int lin = blockIdx.y * gridDim.x + blockIdx.x;
    const int swz = (lin & 7) * 300 + (lin >> 3);
    const int bx  = swz % 10;
    const int yt  = swz / 10;
    const int rowA0 = bx * 128;
    const size_t vRow0 = (size_t)yt * NVP;

    // fragment base pointers (element units); per-chunk advance is the
    // load-instruction immediate offset (c*64 bytes <= 960, fits 13-bit imm)
    const unsigned short* pA[4];
    const unsigned short* pB[7];
    #pragma unroll
    for (int i = 0; i < 4; ++i)
        pA[i] = Abf + ((size_t)(rowA0 + wr * 64 + i * 16 + m16)) * D_ + q * 8;
    #pragma unroll
    for (int j = 0; j < 7; ++j)
        pB[j] = Vbf + (vRow0 + (size_t)(wc * 112 + j * 16 + m16)) * D_ + q * 8;

    f32x4 acc[4][7];
    #pragma unroll
    for (int i = 0; i < 4; ++i)
        #pragma unroll
        for (int j = 0; j < 7; ++j) acc[i][j] = (f32x4)0.0f;

    #pragma unroll
    for (int c = 0; c < 16; ++c) {
        bf16x8 af[4], bv[7];
        #pragma unroll
        for (int i = 0; i < 4; ++i) af[i] = *(const bf16x8*)(pA[i] + c * 32);
        #pragma unroll
        for (int j = 0; j < 7; ++j) bv[j] = *(const bf16x8*)(pB[j] + c * 32);
        #pragma unroll
        for (int i = 0; i < 4; ++i)
            #pragma unroll
            for (int j = 0; j < 7; ++j)
                acc[i][j] = __builtin_amdgcn_mfma_f32_16x16x32_bf16(af[i], bv[j], acc[i][j], 0, 0, 0);
    }

    // ---- clip(s,-20,0)^2 partial sum (zero-padded rows/cols contribute exactly 0) ----
    float cs = 0.0f;
    #pragma unroll
    for (int i = 0; i < 4; ++i)
        #pragma unroll
        for (int j = 0; j < 7; ++j)
            #pragma unroll
            for (int r = 0; r < 4; ++r) {
                float v = acc[i][j][r];
                float cv = fminf(fmaxf(v, -20.0f), 0.0f);
                cs += cv * cv;
            }
    #pragma unroll
    for (int off = 32; off; off >>= 1) cs += __shfl_xor(cs, off, 64);
    if (lane == 0) redbuf[w] = cs;

    // ---- per-row max over valid cols (C/D layout: col=lane&15, row=q*4+reg) ----
    bool colv[7];
    #pragma unroll
    for (int j = 0; j < 7; ++j) colv[j] = (wc * 112 + j * 16 + m16) < NV_;
    #pragma unroll
    for (int i = 0; i < 4; ++i) {
        float mx[4] = {-3e38f, -3e38f, -3e38f, -3e38f};
        #pragma unroll
        for (int j = 0; j < 7; ++j)
            #pragma unroll
            for (int r = 0; r < 4; ++r)
                mx[r] = fmaxf(mx[r], colv[j] ? acc[i][j][r] : -3e38f);
        #pragma unroll
        for (int r = 0; r < 4; ++r) {
            float mm = mx[r];
            #pragma unroll
            for (int off = 1; off <= 8; off <<= 1) mm = fmaxf(mm, __shfl_xor(mm, off, 64));
            if (m16 == 0) maxred[wc][wr * 64 + i * 16 + q * 4 + r] = mm;
        }
    }
    __syncthreads();
    if (tid == 0) atomicAdd(accNonneg, redbuf[0] + redbuf[1] + redbuf[2] + redbuf[3]);
    if (tid < 128) {
        float mm = fmaxf(maxred[0][tid], maxred[1][tid]);
        int R = rowA0 + tid;
        if (R < M_) {
            int x = R / NA_, a = R - x * NA_;
            int y = yt / T_, t = yt - y * T_;
            maxvis[(((size_t)x * B_ + y) * NA_ + a) * T_ + t] = mm;
        }
    }
}

// ---------------- aggregation + last-block finalize ----------------
// 576 blocks x 64 threads. Each block handles one (x,y); the LAST block to
// finish runs the finalize with its 64 threads. Device-scope counter in
// accs[3]; release fence before the counter RMW, acquire fence after.
// Trigger uses (count % 576)==575 so it fires exactly once per 576 arrivals
// even if a profiler replays this dispatch without re-running normconv.
__global__ void aggfin_kernel(const float* __restrict__ maxvis,
                              const float* __restrict__ thrPtr,
                              const float* __restrict__ scalePtr,
                              const float* __restrict__ tempPtr,
                              float* __restrict__ clipSims,
                              float* __restrict__ accs,
                              float* __restrict__ out)
{
    int xy = blockIdx.x;
    int x = xy / B_, y = xy % B_;
    int a = threadIdx.x;
    float th    = 1.0f / (1.0f + expf(-thrPtr[0]));
    float scale = scalePtr[0];
    float token = 0.0f, cnt = 0.0f, selsum = 0.0f;
    if (a < NA_) {
        const float* p = maxvis + (((size_t)x * B_ + y) * NA_ + a) * T_;
        float ws = 0.0f, ss = 0.0f;
        #pragma unroll
        for (int t = 0; t < T_; ++t) {
            float mv  = p[t];
            float rd  = mv - th;
            float sel = fmaxf(rd, 0.0f) * scale;
            ws += mv * sel;
            ss += sel;
            if (rd > 0.0f) cnt += 1.0f;
            if (x == y) selsum += 0.5f * (tanhf(20.0f * rd) + 1.0f);
        }
        token = ws / fmaxf(ss, 1e-6f);
    }
    #pragma unroll
    for (int off = 32; off; off >>= 1) {
        token  += __shfl_xor(token,  off, 64);
        cnt    += __shfl_xor(cnt,    off, 64);
        selsum += __shfl_xor(selsum, off, 64);
    }
    if (threadIdx.x == 0) {
        clipSims[x * B_ + y] = token / (float)NA_;
        atomicAdd(&accs[1], cnt);
        if (x == y) atomicAdd(&accs[2], selsum);
    }
    __threadfence();                      // release: our writes visible device-wide
    unsigned last = 0;
    if (threadIdx.x == 0) {
        unsigned v = atomicAdd((unsigned int*)(accs + 3), 1u);
        last = ((v % (unsigned)(B_ * B_)) == (unsigned)(B_ * B_ - 1));
    }
    last = __shfl((int)last, 0, 64);
    if (!last) return;
    __threadfence();                      // acquire: see all other blocks' writes

    // ---- finalize (64 threads of the last block) ----
    __shared__ float cs[B_ * B_];
    int tid = threadIdx.x;
    for (int i = tid; i < B_ * B_; i += 64) cs[i] = clipSims[i];
    __syncthreads();
    float lsum = 0.0f;
    if (tid < B_) {
        int i = tid;
        float m = -1e30f;
        for (int j = 0; j < B_; ++j) m = fmaxf(m, cs[i * B_ + j]);
        float e = 0.0f;
        for (int j = 0; j < B_; ++j) e += expf(cs[i * B_ + j] - m);
        float la = m + logf(e) - cs[i * B_ + i];
        float m2 = -1e30f;
        for (int j = 0; j < B_; ++j) m2 = fmaxf(m2, cs[j * B_ + i]);
        float e2 = 0.0f;
        for (int j = 0; j < B_; ++j) e2 += expf(cs[j * B_ + i] - m2);
        float lv = m2 + logf(e2) - cs[i * B_ + i];
        lsum = la + lv;
    }
    #pragma unroll
    for (int off = 32; off; off >>= 1) lsum += __shfl_xor(lsum, off, 64);
    if (tid == 0) {
        float contrastive = lsum / (float)B_ * 0.5f;
        float temp = tempPtr[0], scl = scalePtr[0];
        float l_nonneg = accs[0] / 56448000.0f;   // B*B*NA*T*NV
        float logt = logf(temp);
        float tl  = fmaxf(-logt, 0.0f);
        float thi = fmaxf(logt - logf(4.0f), 0.0f);
        float l_cal = tl * tl + thi * thi;
        float t1 = fmaxf(th - 0.9f, 0.0f), t2 = fmaxf(0.1f - th, 0.0f);
        float l_thr = t1 * t1 + t2 * t2;
        float s1 = fmaxf(scl - 20.0f, 0.0f), s2 = fmaxf(1.0f - scl, 0.0f);
        float l_scale = s1 * s1 + s2 * s2;
        float reg = 0.15f * l_nonneg + 2.0f * l_cal + 0.1f * l_thr + 0.1f * l_scale;
        float frac   = accs[1] / 288000.0f;       // B*B*NA*T
        float selrew = -0.1f * log1pf(accs[2] / 12000.0f); // B*NA*T
        out[0] = selrew + contrastive + reg;
        out[1] = contrastive;
        out[2] = reg;
        out[3] = frac;
        out[4] = selrew;
    }
}

extern "C" void kernel_launch(void* const* d_in, const int* in_sizes, int n_in,
                              void* d_out, int out_size, void* d_ws, size_t ws_size,
                              hipStream_t stream) {
    const float* audio  = (const float*)d_in[0];  // (24,50,512)
    const float* visual = (const float*)d_in[1];  // (24,10,196,512)
    const float* temp   = (const float*)d_in[2];
    const float* scale  = (const float*)d_in[3];
    const float* thr    = (const float*)d_in[4];
    float* out = (float*)d_out;

    unsigned char* wsb = (unsigned char*)d_ws;
    unsigned short* Abf = (unsigned short*)wsb;                       // 1280*512*2    = 1,310,720 B
    unsigned short* Vbf = (unsigned short*)(wsb + 1310720);           // 53760*512*2   = 55,050,240 B
    float* maxvis   = (float*)(wsb + 1310720 + 55050240);             // 288000 floats = 1,152,000 B
    float* clipSims = (float*)(wsb + 1310720 + 55050240 + 1152000);   // 576 floats
    float* accs     = clipSims + 576;                                 // 4: [nonneg, frac, sel, counter]

    normconv_kernel<<<ABLK + VROWS / 4, 256, 0, stream>>>(audio, visual, temp, Abf, Vbf, accs);

    dim3 grid(MPAD / 128, YT_);
    simred_kernel<<<grid, 256, 0, stream>>>(Abf, Vbf, maxvis, accs);

    aggfin_kernel<<<B_ * B_, 64, 0, stream>>>(maxvis, thr, scale, temp, clipSims, accs, out);
}

// Round 9
// 277.404 us; speedup vs baseline: 1.4733x; 1.4733x over previous
//
#include <hip/hip_runtime.h>
#include <math.h>

#define B_   24
#define NA_  50
#define T_   10
#define NV_  196
#define D_   512
#define M_   1200          // B*NA audio rows
#define MPAD 1280          // padded to 5 tiles of 256
#define NVP  224           // 196 padded to 14*16
#define YT_  240           // B*T
#define VROWS (YT_ * NVP)  // 53760 padded visual rows
#define ABLK 320           // MPAD/4 blocks handle audio in fused normconv

#define NT    16           // K-steps (BK=32)
#define BUFB  32768u       // per-step buffer: A 16KB + V 14KB + 2KB scratch
#define VBASE 16384u

typedef __bf16 bf16x8 __attribute__((ext_vector_type(8)));
typedef float  f32x4  __attribute__((ext_vector_type(4)));
typedef unsigned short ushort8 __attribute__((ext_vector_type(8)));

__device__ __forceinline__ unsigned short f2bf(float f) {
    unsigned u = __float_as_uint(f);
    u += 0x7FFF + ((u >> 16) & 1);       // RNE
    return (unsigned short)(u >> 16);
}

__device__ __forceinline__ void gload16(const void* g, void* l) {
    __builtin_amdgcn_global_load_lds(
        (const __attribute__((address_space(1))) unsigned int*)g,
        (__attribute__((address_space(3))) unsigned int*)l, 16, 0, 0);
}

// ---- fused L2-normalize + bf16 convert for BOTH inputs, + accs/counter zeroing ----
__global__ void normconv_kernel(const float* __restrict__ a,
                                const float* __restrict__ vf,
                                const float* __restrict__ tempPtr,
                                unsigned short* __restrict__ Abf,
                                unsigned short* __restrict__ Vbf,
                                float* __restrict__ accs) {
    if (blockIdx.x == 0 && threadIdx.x < 4) accs[threadIdx.x] = 0.0f; // [nonneg,frac,sel,counter]
    int w = threadIdx.x >> 6, lane = threadIdx.x & 63;
    int bid = blockIdx.x;
    const float* src = nullptr;
    ushort8* dst;
    float tscale = 1.0f;
    if (bid < ABLK) {
        int row = bid * 4 + w;                 // < MPAD
        dst = (ushort8*)(Abf + (size_t)row * D_ + lane * 8);
        if (row < M_) { src = a + (size_t)row * D_ + lane * 8; tscale = tempPtr[0]; }
    } else {
        int row = (bid - ABLK) * 4 + w;        // < VROWS
        dst = (ushort8*)(Vbf + (size_t)row * D_ + lane * 8);
        int yt = row / NVP, vv = row - yt * NVP;
        if (vv < NV_) src = vf + ((size_t)yt * NV_ + vv) * D_ + lane * 8;
    }
    if (src) {
        float4 u = *(const float4*)src;
        float4 v = *(const float4*)(src + 4);
        float s = u.x*u.x + u.y*u.y + u.z*u.z + u.w*u.w
                + v.x*v.x + v.y*v.y + v.z*v.z + v.w*v.w;
        #pragma unroll
        for (int off = 32; off; off >>= 1) s += __shfl_xor(s, off, 64);
        float sc = 1.0f / (fmaxf(sqrtf(s), 1e-12f) * tscale);
        ushort8 o;
        o[0]=f2bf(u.x*sc); o[1]=f2bf(u.y*sc); o[2]=f2bf(u.z*sc); o[3]=f2bf(u.w*sc);
        o[4]=f2bf(v.x*sc); o[5]=f2bf(v.y*sc); o[6]=f2bf(v.z*sc); o[7]=f2bf(v.w*sc);
        *dst = o;
    } else {
        ushort8 z = (ushort8)0;
        *dst = z;
    }
}

// ---- MFMA GEMM + fused max/clip reductions: counted-vmcnt depth-2 pipeline ----
// 256x224 tile, 8 waves (4x2), BK=32, double-buffered 2x32KB LDS.
// THE structural change vs R3/R5/R7: NO __syncthreads in the K-loop (its
// implicit vmcnt(0) drains the prefetch queue - the documented ~m97 stall).
// Instead: raw s_barrier + counted waits. Per step:
//   ds_read frags(t) -> lgkmcnt(0)+s_barrier (WAR: all waves done with buf)
//   -> STAGE(t+2) into the buffer just read -> MFMA(t)
//   -> vmcnt(4)+s_barrier (own STAGE(t+1) landed; t+2's 4 loads STAY IN FLIGHT).
// Staging loads are the coalesced-friendly shape (lane i -> base+16i, one 1KB
// segment) - R8 proved scattered direct fragment loads cost ~5x in the TA.
// XCD bijective swizzle (R3: FETCH 229->32MB) + 16B-granule XOR LDS swizzle
// (R1: conflicts 6.76M->0) retained. maxred/redbuf reuse the staging scratch
// slots after the loop (keeps LDS at exactly 64KB).
__global__ __launch_bounds__(512, 1) void simred_kernel(
    const unsigned short* __restrict__ Abf, const unsigned short* __restrict__ Vbf,
    float* __restrict__ maxvis, float* __restrict__ accNonneg)
{
    __shared__ __align__(16) unsigned char lds[2 * BUFB];
    float* maxredp = (float*)(lds + 30720);          // 512 f32 in buf0 scratch (post-loop reuse)
    float* redbufp = (float*)(lds + BUFB + 30720);   // 8 f32 in buf1 scratch

    const int tid  = threadIdx.x;
    const int lane = tid & 63;
    const int w    = tid >> 6;     // 8 waves
    const int lrow = lane >> 2;    // staging: row within 16-row unit
    const int lcol = lane & 3;     // staging: 16B granule within 64B row-slice
    const int q    = lane >> 4;    // frag quad
    const int m16  = lane & 15;
    const int wr   = w & 3;        // wave row quarter (64 rows)
    const int wc   = w >> 2;       // wave col half (112 cols)

    // XCD-aware bijective remap: 1200 blocks, 8 XCDs, 150/XCD (yt-partitioned)
    const int lin = blockIdx.y * gridDim.x + blockIdx.x;
    const int swz = (lin & 7) * 150 + (lin >> 3);
    const int bx  = swz % 5;
    const int yt  = swz / 5;
    const int rowA0 = bx * 256;
    const size_t vRow0 = (size_t)yt * NVP;

    // staging units (1KB each): 0..15 = A rows u*16.., 16..29 = V rows (u-16)*16..,
    // 30..31 = per-wave dummy scratch (uniform 4 loads/wave -> uniform vmcnt immediates).
    // Source col pre-swizzled (granule ^= (row>>1)&3); LDS dest linear.
    const int scol = lcol ^ ((lrow >> 1) & 3);
    const unsigned short* gp[4];
    unsigned loff[4];
    #pragma unroll
    for (int k = 0; k < 4; ++k) {
        int u = w + 8 * k;
        if (u < 16)      gp[k] = Abf + ((size_t)(rowA0 + u * 16 + lrow)) * D_ + scol * 8;
        else if (u < 30) gp[k] = Vbf + (vRow0 + (size_t)((u - 16) * 16 + lrow)) * D_ + scol * 8;
        else             gp[k] = Abf + (size_t)lane * 8;   // dummy: valid mem, never read
        loff[k] = (unsigned)u * 1024u;
    }

    // fragment read offsets (row*64B + swizzled granule), R3-verified scheme
    const unsigned rsw = (unsigned)((m16 >> 1) & 3) * 16u;
    unsigned aoff[4], boff[7];
    #pragma unroll
    for (int i = 0; i < 4; ++i)
        aoff[i] = (unsigned)(wr * 64 + i * 16 + m16) * 64u + (((unsigned)q * 16u) ^ rsw);
    #pragma unroll
    for (int j = 0; j < 7; ++j)
        boff[j] = VBASE + (unsigned)(wc * 112 + j * 16 + m16) * 64u + (((unsigned)q * 16u) ^ rsw);

    f32x4 acc[4][7];
    #pragma unroll
    for (int i = 0; i < 4; ++i)
        #pragma unroll
        for (int j = 0; j < 7; ++j) acc[i][j] = (f32x4)0.0f;

    // prologue: STAGE(0)->buf0, STAGE(1)->buf1, wait only for STAGE(0)
    #pragma unroll
    for (int k = 0; k < 4; ++k) gload16(gp[k], (void*)(lds + loff[k]));
    #pragma unroll
    for (int k = 0; k < 4; ++k) gload16(gp[k] + 32, (void*)(lds + BUFB + loff[k]));
    asm volatile("s_waitcnt vmcnt(4)\ns_barrier" ::: "memory");

    #pragma unroll 2
    for (int t = 0; t < NT; ++t) {
        const unsigned char* buf = lds + (unsigned)(t & 1) * BUFB;
        bf16x8 af[4], bv[7];
        #pragma unroll
        for (int i = 0; i < 4; ++i) af[i] = *(const bf16x8*)(buf + aoff[i]);
        #pragma unroll
        for (int j = 0; j < 7; ++j) bv[j] = *(const bf16x8*)(buf + boff[j]);
        // WAR guard: every wave's reads drained, then block-wide rendezvous
        asm volatile("s_waitcnt lgkmcnt(0)\ns_barrier" ::: "memory");
        __builtin_amdgcn_sched_barrier(0);
        if (t < NT - 2) {
            const int kc2 = (t + 2) * 32;
            #pragma unroll
            for (int k = 0; k < 4; ++k)
                gload16(gp[k] + kc2, (void*)(lds + (unsigned)(t & 1) * BUFB + loff[k]));
        }
        __builtin_amdgcn_sched_barrier(0);
        __builtin_amdgcn_s_setprio(1);
        #pragma unroll
        for (int i = 0; i < 4; ++i)
            #pragma unroll
            for (int j = 0; j < 7; ++j)
                acc[i][j] = __builtin_amdgcn_mfma_f32_16x16x32_bf16(af[i], bv[j], acc[i][j], 0, 0, 0);
        __builtin_amdgcn_s_setprio(0);
        // RAW guard for next step: own STAGE(t+1) landed (4 newest stay in flight)
        if (t < NT - 2)       asm volatile("s_waitcnt vmcnt(4)\ns_barrier" ::: "memory");
        else if (t == NT - 2) asm volatile("s_waitcnt vmcnt(0)\ns_barrier" ::: "memory");
        // t == NT-1: no further buffer use
    }

    // ---- clip(s,-20,0)^2 partial sum (zero-padded rows/cols contribute exactly 0) ----
    float cs = 0.0f;
    #pragma unroll
    for (int i = 0; i < 4; ++i)
        #pragma unroll
        for (int j = 0; j < 7; ++j)
            #pragma unroll
            for (int r = 0; r < 4; ++r) {
                float v = acc[i][j][r];
                float cv = fminf(fmaxf(v, -20.0f), 0.0f);
                cs += cv * cv;
            }
    #pragma unroll
    for (int off = 32; off; off >>= 1) cs += __shfl_xor(cs, off, 64);
    if (lane == 0) redbufp[w] = cs;

    // ---- per-row max over valid cols (C/D layout: col=lane&15, row=q*4+reg) ----
    bool colv[7];
    #pragma unroll
    for (int j = 0; j < 7; ++j) colv[j] = (wc * 112 + j * 16 + m16) < NV_;
    #pragma unroll
    for (int i = 0; i < 4; ++i) {
        float mx[4] = {-3e38f, -3e38f, -3e38f, -3e38f};
        #pragma unroll
        for (int j = 0; j < 7; ++j)
            #pragma unroll
            for (int r = 0; r < 4; ++r)
                mx[r] = fmaxf(mx[r], colv[j] ? acc[i][j][r] : -3e38f);
        #pragma unroll
        for (int r = 0; r < 4; ++r) {
            float mm = mx[r];
            #pragma unroll
            for (int off = 1; off <= 8; off <<= 1) mm = fmaxf(mm, __shfl_xor(mm, off, 64));
            if (m16 == 0) maxredp[wc * 256 + wr * 64 + i * 16 + q * 4 + r] = mm;
        }
    }
    __syncthreads();
    if (tid == 0) atomicAdd(accNonneg, redbufp[0] + redbufp[1] + redbufp[2] + redbufp[3]
                                     + redbufp[4] + redbufp[5] + redbufp[6] + redbufp[7]);
    if (tid < 256) {
        float mm = fmaxf(maxredp[tid], maxredp[256 + tid]);
        int R = rowA0 + tid;
        if (R < M_) {
            int x = R / NA_, a = R - x * NA_;
            int y = yt / T_, t = yt - y * T_;
            maxvis[(((size_t)x * B_ + y) * NA_ + a) * T_ + t] = mm;
        }
    }
}

// ---------------- aggregation + last-block finalize ----------------
__global__ void aggfin_kernel(const float* __restrict__ maxvis,
                              const float* __restrict__ thrPtr,
                              const float* __restrict__ scalePtr,
                              const float* __restrict__ tempPtr,
                              float* __restrict__ clipSims,
                              float* __restrict__ accs,
                              float* __restrict__ out)
{
    int xy = blockIdx.x;
    int x = xy / B_, y = xy % B_;
    int a = threadIdx.x;
    float th    = 1.0f / (1.0f + expf(-thrPtr[0]));
    float scale = scalePtr[0];
    float token = 0.0f, cnt = 0.0f, selsum = 0.0f;
    if (a < NA_) {
        const float* p = maxvis + (((size_t)x * B_ + y) * NA_ + a) * T_;
        float ws = 0.0f, ss = 0.0f;
        #pragma unroll
        for (int t = 0; t < T_; ++t) {
            float mv  = p[t];
            float rd  = mv - th;
            float sel = fmaxf(rd, 0.0f) * scale;
            ws += mv * sel;
            ss += sel;
            if (rd > 0.0f) cnt += 1.0f;
            if (x == y) selsum += 0.5f * (tanhf(20.0f * rd) + 1.0f);
        }
        token = ws / fmaxf(ss, 1e-6f);
    }
    #pragma unroll
    for (int off = 32; off; off >>= 1) {
        token  += __shfl_xor(token,  off, 64);
        cnt    += __shfl_xor(cnt,    off, 64);
        selsum += __shfl_xor(selsum, off, 64);
    }
    if (threadIdx.x == 0) {
        clipSims[x * B_ + y] = token / (float)NA_;
        atomicAdd(&accs[1], cnt);
        if (x == y) atomicAdd(&accs[2], selsum);
    }
    __threadfence();                      // release
    unsigned last = 0;
    if (threadIdx.x == 0) {
        unsigned v = atomicAdd((unsigned int*)(accs + 3), 1u);
        last = ((v % (unsigned)(B_ * B_)) == (unsigned)(B_ * B_ - 1));
    }
    last = __shfl((int)last, 0, 64);
    if (!last) return;
    __threadfence();                      // acquire

    __shared__ float cs[B_ * B_];
    int tid = threadIdx.x;
    for (int i = tid; i < B_ * B_; i += 64) cs[i] = clipSims[i];
    __syncthreads();
    float lsum = 0.0f;
    if (tid < B_) {
        int i = tid;
        float m = -1e30f;
        for (int j = 0; j < B_; ++j) m = fmaxf(m, cs[i * B_ + j]);
        float e = 0.0f;
        for (int j = 0; j < B_; ++j) e += expf(cs[i * B_ + j] - m);
        float la = m + logf(e) - cs[i * B_ + i];
        float m2 = -1e30f;
        for (int j = 0; j < B_; ++j) m2 = fmaxf(m2, cs[j * B_ + i]);
        float e2 = 0.0f;
        for (int j = 0; j < B_; ++j) e2 += expf(cs[j * B_ + i] - m2);
        float lv = m2 + logf(e2) - cs[i * B_ + i];
        lsum = la + lv;
    }
    #pragma unroll
    for (int off = 32; off; off >>= 1) lsum += __shfl_xor(lsum, off, 64);
    if (tid == 0) {
        float contrastive = lsum / (float)B_ * 0.5f;
        float temp = tempPtr[0], scl = scalePtr[0];
        float l_nonneg = accs[0] / 56448000.0f;   // B*B*NA*T*NV
        float logt = logf(temp);
        float tl  = fmaxf(-logt, 0.0f);
        float thi = fmaxf(logt - logf(4.0f), 0.0f);
        float l_cal = tl * tl + thi * thi;
        float t1 = fmaxf(th - 0.9f, 0.0f), t2 = fmaxf(0.1f - th, 0.0f);
        float l_thr = t1 * t1 + t2 * t2;
        float s1 = fmaxf(scl - 20.0f, 0.0f), s2 = fmaxf(1.0f - scl, 0.0f);
        float l_scale = s1 * s1 + s2 * s2;
        float reg = 0.15f * l_nonneg + 2.0f * l_cal + 0.1f * l_thr + 0.1f * l_scale;
        float frac   = accs[1] / 288000.0f;       // B*B*NA*T
        float selrew = -0.1f * log1pf(accs[2] / 12000.0f); // B*NA*T
        out[0] = selrew + contrastive + reg;
        out[1] = contrastive;
        out[2] = reg;
        out[3] = frac;
        out[4] = selrew;
    }
}

extern "C" void kernel_launch(void* const* d_in, const int* in_sizes, int n_in,
                              void* d_out, int out_size, void* d_ws, size_t ws_size,
                              hipStream_t stream) {
    const float* audio  = (const float*)d_in[0];  // (24,50,512)
    const float* visual = (const float*)d_in[1];  // (24,10,196,512)
    const float* temp   = (const float*)d_in[2];
    const float* scale  = (const float*)d_in[3];
    const float* thr    = (const float*)d_in[4];
    float* out = (float*)d_out;

    unsigned char* wsb = (unsigned char*)d_ws;
    unsigned short* Abf = (unsigned short*)wsb;                       // 1280*512*2
    unsigned short* Vbf = (unsigned short*)(wsb + 1310720);           // 53760*512*2
    float* maxvis   = (float*)(wsb + 1310720 + 55050240);             // 288000 floats
    float* clipSims = (float*)(wsb + 1310720 + 55050240 + 1152000);   // 576 floats
    float* accs     = clipSims + 576;                                 // [nonneg, frac, sel, counter]

    normconv_kernel<<<ABLK + VROWS / 4, 256, 0, stream>>>(audio, visual, temp, Abf, Vbf, accs);

    dim3 grid(MPAD / 256, YT_);
    simred_kernel<<<grid, 512, 0, stream>>>(Abf, Vbf, maxvis, accs);

    aggfin_kernel<<<B_ * B_, 64, 0, stream>>>(maxvis, thr, scale, temp, clipSims, accs, out);
}

// Round 10
// 266.759 us; speedup vs baseline: 1.5321x; 1.0399x over previous
//
#include <hip/hip_runtime.h>
#include <math.h>

#define B_   24
#define NA_  50
#define T_   10
#define NV_  196
#define D_   512
#define M_   1200          // B*NA audio rows
#define MPAD 1280          // padded to 5 tiles of 256
#define NVP  224           // 196 padded to 14*16
#define YT_  240           // B*T
#define VROWS (YT_ * NVP)  // 53760 padded visual rows
#define ABLK 320           // MPAD/4 blocks handle audio in fused normconv

#define NT    16           // K-steps (BK=32)
#define BUFB  32768u       // per-step buffer: A 16KB + V 14KB + 2KB scratch
#define VBASE 16384u

typedef __bf16 bf16x8 __attribute__((ext_vector_type(8)));
typedef float  f32x4  __attribute__((ext_vector_type(4)));
typedef unsigned short ushort8 __attribute__((ext_vector_type(8)));

__device__ __forceinline__ unsigned short f2bf(float f) {
    unsigned u = __float_as_uint(f);
    u += 0x7FFF + ((u >> 16) & 1);       // RNE
    return (unsigned short)(u >> 16);
}

__device__ __forceinline__ void gload16(const void* g, void* l) {
    __builtin_amdgcn_global_load_lds(
        (const __attribute__((address_space(1))) unsigned int*)g,
        (__attribute__((address_space(3))) unsigned int*)l, 16, 0, 0);
}

// ---- fused L2-normalize + bf16 convert for BOTH inputs, + accs/counter zeroing ----
__global__ void normconv_kernel(const float* __restrict__ a,
                                const float* __restrict__ vf,
                                const float* __restrict__ tempPtr,
                                unsigned short* __restrict__ Abf,
                                unsigned short* __restrict__ Vbf,
                                float* __restrict__ accs) {
    if (blockIdx.x == 0 && threadIdx.x < 4) accs[threadIdx.x] = 0.0f; // [nonneg,frac,sel,counter]
    int w = threadIdx.x >> 6, lane = threadIdx.x & 63;
    int bid = blockIdx.x;
    const float* src = nullptr;
    ushort8* dst;
    float tscale = 1.0f;
    if (bid < ABLK) {
        int row = bid * 4 + w;                 // < MPAD
        dst = (ushort8*)(Abf + (size_t)row * D_ + lane * 8);
        if (row < M_) { src = a + (size_t)row * D_ + lane * 8; tscale = tempPtr[0]; }
    } else {
        int row = (bid - ABLK) * 4 + w;        // < VROWS
        dst = (ushort8*)(Vbf + (size_t)row * D_ + lane * 8);
        int yt = row / NVP, vv = row - yt * NVP;
        if (vv < NV_) src = vf + ((size_t)yt * NV_ + vv) * D_ + lane * 8;
    }
    if (src) {
        float4 u = *(const float4*)src;
        float4 v = *(const float4*)(src + 4);
        float s = u.x*u.x + u.y*u.y + u.z*u.z + u.w*u.w
                + v.x*v.x + v.y*v.y + v.z*v.z + v.w*v.w;
        #pragma unroll
        for (int off = 32; off; off >>= 1) s += __shfl_xor(s, off, 64);
        float sc = 1.0f / (fmaxf(sqrtf(s), 1e-12f) * tscale);
        ushort8 o;
        o[0]=f2bf(u.x*sc); o[1]=f2bf(u.y*sc); o[2]=f2bf(u.z*sc); o[3]=f2bf(u.w*sc);
        o[4]=f2bf(v.x*sc); o[5]=f2bf(v.y*sc); o[6]=f2bf(v.z*sc); o[7]=f2bf(v.w*sc);
        *dst = o;
    } else {
        ushort8 z = (ushort8)0;
        *dst = z;
    }
}

// ---- MFMA GEMM + fused max/clip reductions: pipe-overlapped K-loop ----
// R9 found per-step time 3325cyc vs MFMA 1086 + ds_read 1056 (separate pipes,
// but phase-serialized by the lockstep schedule). This version overlaps them:
// register-double-buffered fragments (sets A/B, unrolled x2 for static regs),
// ONE barrier + ONE combined wait per step:
//   top(t): vmcnt(0)+lgkmcnt(0)+s_barrier   (frag(t) reads done all waves;
//                                            STAGE(t+1) landed all waves)
//   STAGE(t+2) -> buf[t&1]                  (WAR-safe; flies a full cluster)
//   ds_read frags(t+1) from buf[(t+1)&1]    (RAW-safe; lands during MFMA(t))
//   MFMA frags(t)                           (matrix pipe || LDS pipe)
// vmcnt(0) here waits a stage issued a full cluster earlier (~free) - NOT
// the m97 issue-then-drain pattern. XCD bijective swizzle (FETCH 229->32MB,
// R3) + both-sides 16B-granule XOR LDS swizzle (conflicts->0, R1) retained.
#define RD_FRAGS(AF, BV, BASE)                                                  \
    _Pragma("unroll") for (int i = 0; i < 4; ++i)                               \
        AF[i] = *(const bf16x8*)((BASE) + aoff[i]);                             \
    _Pragma("unroll") for (int j = 0; j < 7; ++j)                               \
        BV[j] = *(const bf16x8*)((BASE) + boff[j]);

#define MFMA_ALL(AF, BV)                                                        \
    _Pragma("unroll") for (int i = 0; i < 4; ++i)                               \
        _Pragma("unroll") for (int j = 0; j < 7; ++j)                           \
            acc[i][j] = __builtin_amdgcn_mfma_f32_16x16x32_bf16(AF[i], BV[j], acc[i][j], 0, 0, 0);

#define STAGE_T(T, BASEOFF)                                                     \
    _Pragma("unroll") for (int k = 0; k < 4; ++k)                               \
        gload16(gp[k] + (T) * 32, (void*)(lds + (BASEOFF) + loff[k]));

__global__ __launch_bounds__(512, 1) void simred_kernel(
    const unsigned short* __restrict__ Abf, const unsigned short* __restrict__ Vbf,
    float* __restrict__ maxvis, float* __restrict__ accNonneg)
{
    __shared__ __align__(16) unsigned char lds[2 * BUFB];
    float* maxredp = (float*)(lds + 30720);          // 512 f32 in buf0 scratch (post-loop reuse)
    float* redbufp = (float*)(lds + BUFB + 30720);   // 8 f32 in buf1 scratch

    const int tid  = threadIdx.x;
    const int lane = tid & 63;
    const int w    = tid >> 6;     // 8 waves
    const int lrow = lane >> 2;    // staging: row within 16-row unit
    const int lcol = lane & 3;     // staging: 16B granule within 64B row-slice
    const int q    = lane >> 4;    // frag quad
    const int m16  = lane & 15;
    const int wr   = w & 3;        // wave row quarter (64 rows)
    const int wc   = w >> 2;       // wave col half (112 cols)

    // XCD-aware bijective remap: 1200 blocks, 8 XCDs, 150/XCD (yt-partitioned)
    const int lin = blockIdx.y * gridDim.x + blockIdx.x;
    const int swz = (lin & 7) * 150 + (lin >> 3);
    const int bx  = swz % 5;
    const int yt  = swz / 5;
    const int rowA0 = bx * 256;
    const size_t vRow0 = (size_t)yt * NVP;

    // staging units (1KB each): 0..15 = A rows, 16..29 = V rows, 30..31 dummy
    // (uniform 4 loads/wave -> uniform per-wave vmcnt). Source granule
    // pre-swizzled; LDS dest linear.
    const int scol = lcol ^ ((lrow >> 1) & 3);
    const unsigned short* gp[4];
    unsigned loff[4];
    #pragma unroll
    for (int k = 0; k < 4; ++k) {
        int u = w + 8 * k;
        if (u < 16)      gp[k] = Abf + ((size_t)(rowA0 + u * 16 + lrow)) * D_ + scol * 8;
        else if (u < 30) gp[k] = Vbf + (vRow0 + (size_t)((u - 16) * 16 + lrow)) * D_ + scol * 8;
        else             gp[k] = Abf + (size_t)lane * 8;   // dummy: valid mem, never read
        loff[k] = (unsigned)u * 1024u;
    }

    // fragment read offsets (row*64B + swizzled 16B granule)
    const unsigned rsw = (unsigned)((m16 >> 1) & 3) * 16u;
    unsigned aoff[4], boff[7];
    #pragma unroll
    for (int i = 0; i < 4; ++i)
        aoff[i] = (unsigned)(wr * 64 + i * 16 + m16) * 64u + (((unsigned)q * 16u) ^ rsw);
    #pragma unroll
    for (int j = 0; j < 7; ++j)
        boff[j] = VBASE + (unsigned)(wc * 112 + j * 16 + m16) * 64u + (((unsigned)q * 16u) ^ rsw);

    f32x4 acc[4][7];
    #pragma unroll
    for (int i = 0; i < 4; ++i)
        #pragma unroll
        for (int j = 0; j < 7; ++j) acc[i][j] = (f32x4)0.0f;

    bf16x8 afA[4], bvA[7], afB[4], bvB[7];

    // prologue: STAGE(0)->b0, STAGE(1)->b1; all waves' STAGE(0) resident; frags(0)->A
    STAGE_T(0, 0u)
    STAGE_T(1, BUFB)
    asm volatile("s_waitcnt vmcnt(4)\ns_barrier" ::: "memory");
    RD_FRAGS(afA, bvA, lds)

    #pragma unroll
    for (int tp = 0; tp < 8; ++tp) {
        const int t = 2 * tp;
        // ---- even step t: compute A (from b0), read frags(t+1) b1 -> B ----
        asm volatile("s_waitcnt vmcnt(0) lgkmcnt(0)\ns_barrier" ::: "memory");
        if (t + 2 < NT) { STAGE_T(t + 2, 0u) }          // -> b0 (just fully read)
        RD_FRAGS(afB, bvB, lds + BUFB)                  // frags(t+1); t+1 <= 15 always
        __builtin_amdgcn_s_setprio(1);
        MFMA_ALL(afA, bvA)
        __builtin_amdgcn_s_setprio(0);
        // ---- odd step t+1: compute B (from b1), read frags(t+2) b0 -> A ----
        asm volatile("s_waitcnt vmcnt(0) lgkmcnt(0)\ns_barrier" ::: "memory");
        if (t + 3 < NT) { STAGE_T(t + 3, BUFB) }        // -> b1
        if (t + 2 < NT) { RD_FRAGS(afA, bvA, lds) }     // frags(t+2)
        __builtin_amdgcn_s_setprio(1);
        MFMA_ALL(afB, bvB)
        __builtin_amdgcn_s_setprio(0);
    }

    // ---- clip(s,-20,0)^2 partial sum (zero-padded rows/cols contribute exactly 0) ----
    float cs = 0.0f;
    #pragma unroll
    for (int i = 0; i < 4; ++i)
        #pragma unroll
        for (int j = 0; j < 7; ++j)
            #pragma unroll
            for (int r = 0; r < 4; ++r) {
                float v = acc[i][j][r];
                float cv = fminf(fmaxf(v, -20.0f), 0.0f);
                cs += cv * cv;
            }
    #pragma unroll
    for (int off = 32; off; off >>= 1) cs += __shfl_xor(cs, off, 64);
    if (lane == 0) redbufp[w] = cs;

    // ---- per-row max over valid cols (C/D layout: col=lane&15, row=q*4+reg) ----
    bool colv[7];
    #pragma unroll
    for (int j = 0; j < 7; ++j) colv[j] = (wc * 112 + j * 16 + m16) < NV_;
    #pragma unroll
    for (int i = 0; i < 4; ++i) {
        float mx[4] = {-3e38f, -3e38f, -3e38f, -3e38f};
        #pragma unroll
        for (int j = 0; j < 7; ++j)
            #pragma unroll
            for (int r = 0; r < 4; ++r)
                mx[r] = fmaxf(mx[r], colv[j] ? acc[i][j][r] : -3e38f);
        #pragma unroll
        for (int r = 0; r < 4; ++r) {
            float mm = mx[r];
            #pragma unroll
            for (int off = 1; off <= 8; off <<= 1) mm = fmaxf(mm, __shfl_xor(mm, off, 64));
            if (m16 == 0) maxredp[wc * 256 + wr * 64 + i * 16 + q * 4 + r] = mm;
        }
    }
    __syncthreads();
    if (tid == 0) atomicAdd(accNonneg, redbufp[0] + redbufp[1] + redbufp[2] + redbufp[3]
                                     + redbufp[4] + redbufp[5] + redbufp[6] + redbufp[7]);
    if (tid < 256) {
        float mm = fmaxf(maxredp[tid], maxredp[256 + tid]);
        int R = rowA0 + tid;
        if (R < M_) {
            int x = R / NA_, a = R - x * NA_;
            int y = yt / T_, t = yt - y * T_;
            maxvis[(((size_t)x * B_ + y) * NA_ + a) * T_ + t] = mm;
        }
    }
}

// ---------------- aggregation + last-block finalize ----------------
__global__ void aggfin_kernel(const float* __restrict__ maxvis,
                              const float* __restrict__ thrPtr,
                              const float* __restrict__ scalePtr,
                              const float* __restrict__ tempPtr,
                              float* __restrict__ clipSims,
                              float* __restrict__ accs,
                              float* __restrict__ out)
{
    int xy = blockIdx.x;
    int x = xy / B_, y = xy % B_;
    int a = threadIdx.x;
    float th    = 1.0f / (1.0f + expf(-thrPtr[0]));
    float scale = scalePtr[0];
    float token = 0.0f, cnt = 0.0f, selsum = 0.0f;
    if (a < NA_) {
        const float* p = maxvis + (((size_t)x * B_ + y) * NA_ + a) * T_;
        float ws = 0.0f, ss = 0.0f;
        #pragma unroll
        for (int t = 0; t < T_; ++t) {
            float mv  = p[t];
            float rd  = mv - th;
            float sel = fmaxf(rd, 0.0f) * scale;
            ws += mv * sel;
            ss += sel;
            if (rd > 0.0f) cnt += 1.0f;
            if (x == y) selsum += 0.5f * (tanhf(20.0f * rd) + 1.0f);
        }
        token = ws / fmaxf(ss, 1e-6f);
    }
    #pragma unroll
    for (int off = 32; off; off >>= 1) {
        token  += __shfl_xor(token,  off, 64);
        cnt    += __shfl_xor(cnt,    off, 64);
        selsum += __shfl_xor(selsum, off, 64);
    }
    if (threadIdx.x == 0) {
        clipSims[x * B_ + y] = token / (float)NA_;
        atomicAdd(&accs[1], cnt);
        if (x == y) atomicAdd(&accs[2], selsum);
    }
    __threadfence();                      // release
    unsigned last = 0;
    if (threadIdx.x == 0) {
        unsigned v = atomicAdd((unsigned int*)(accs + 3), 1u);
        last = ((v % (unsigned)(B_ * B_)) == (unsigned)(B_ * B_ - 1));
    }
    last = __shfl((int)last, 0, 64);
    if (!last) return;
    __threadfence();                      // acquire

    __shared__ float cs[B_ * B_];
    int tid = threadIdx.x;
    for (int i = tid; i < B_ * B_; i += 64) cs[i] = clipSims[i];
    __syncthreads();
    float lsum = 0.0f;
    if (tid < B_) {
        int i = tid;
        float m = -1e30f;
        for (int j = 0; j < B_; ++j) m = fmaxf(m, cs[i * B_ + j]);
        float e = 0.0f;
        for (int j = 0; j < B_; ++j) e += expf(cs[i * B_ + j] - m);
        float la = m + logf(e) - cs[i * B_ + i];
        float m2 = -1e30f;
        for (int j = 0; j < B_; ++j) m2 = fmaxf(m2, cs[j * B_ + i]);
        float e2 = 0.0f;
        for (int j = 0; j < B_; ++j) e2 += expf(cs[j * B_ + i] - m2);
        float lv = m2 + logf(e2) - cs[i * B_ + i];
        lsum = la + lv;
    }
    #pragma unroll
    for (int off = 32; off; off >>= 1) lsum += __shfl_xor(lsum, off, 64);
    if (tid == 0) {
        float contrastive = lsum / (float)B_ * 0.5f;
        float temp = tempPtr[0], scl = scalePtr[0];
        float th2 = 1.0f / (1.0f + expf(-thrPtr[0]));
        float l_nonneg = accs[0] / 56448000.0f;   // B*B*NA*T*NV
        float logt = logf(temp);
        float tl  = fmaxf(-logt, 0.0f);
        float thi = fmaxf(logt - logf(4.0f), 0.0f);
        float l_cal = tl * tl + thi * thi;
        float t1 = fmaxf(th2 - 0.9f, 0.0f), t2 = fmaxf(0.1f - th2, 0.0f);
        float l_thr = t1 * t1 + t2 * t2;
        float s1 = fmaxf(scl - 20.0f, 0.0f), s2 = fmaxf(1.0f - scl, 0.0f);
        float l_scale = s1 * s1 + s2 * s2;
        float reg = 0.15f * l_nonneg + 2.0f * l_cal + 0.1f * l_thr + 0.1f * l_scale;
        float frac   = accs[1] / 288000.0f;       // B*B*NA*T
        float selrew = -0.1f * log1pf(accs[2] / 12000.0f); // B*NA*T
        out[0] = selrew + contrastive + reg;
        out[1] = contrastive;
        out[2] = reg;
        out[3] = frac;
        out[4] = selrew;
    }
}

extern "C" void kernel_launch(void* const* d_in, const int* in_sizes, int n_in,
                              void* d_out, int out_size, void* d_ws, size_t ws_size,
                              hipStream_t stream) {
    const float* audio  = (const float*)d_in[0];  // (24,50,512)
    const float* visual = (const float*)d_in[1];  // (24,10,196,512)
    const float* temp   = (const float*)d_in[2];
    const float* scale  = (const float*)d_in[3];
    const float* thr    = (const float*)d_in[4];
    float* out = (float*)d_out;

    unsigned char* wsb = (unsigned char*)d_ws;
    unsigned short* Abf = (unsigned short*)wsb;                       // 1280*512*2
    unsigned short* Vbf = (unsigned short*)(wsb + 1310720);           // 53760*512*2
    float* maxvis   = (float*)(wsb + 1310720 + 55050240);             // 288000 floats
    float* clipSims = (float*)(wsb + 1310720 + 55050240 + 1152000);   // 576 floats
    float* accs     = clipSims + 576;                                 // [nonneg, frac, sel, counter]

    normconv_kernel<<<ABLK + VROWS / 4, 256, 0, stream>>>(audio, visual, temp, Abf, Vbf, accs);

    dim3 grid(MPAD / 256, YT_);
    simred_kernel<<<grid, 512, 0, stream>>>(Abf, Vbf, maxvis, accs);

    aggfin_kernel<<<B_ * B_, 64, 0, stream>>>(maxvis, thr, scale, temp, clipSims, accs, out);
}